// Round 3
// baseline (11.815 us; speedup 1.0000x reference)
//
#include <hip/hip_runtime.h>

// Problem constants (match reference): B=4, C=64, N=1024, H=8, D=8
#define BATCH 4
#define CH    64
#define NSEQ  1024
#define NQUARTER 256
// inv_sqrt_d = 1/sqrt(8)
#define INV_SQRT_D 0.35355339059327373f

// Algebraic collapse (verified R0/R1, absmax 0.0):
//   softmax over keys of (q-k)/s == softmax(-k/s)  -> q, Wq dead;
//   out[b,c,n] = o[b,c] for all n,
//   o[b,c] = sum_m exp(-K[b,c,m]/sqrt(D)) * V[b,c,m] / sum_m exp(-K[b,c,m]/sqrt(D))
//   (unstabilized exp is safe: K ~ N(0,1), |score| ~< 2).
//
// R2 structure: unstabilized softmax => partial (sum_e, sum_e*v) over disjoint
// n-ranges are addable => split N across blocks.
//   K1: 1024 blocks = (bc, quarter) x 256 thr. 4 independent blocks/CU
//       (vs R1's single 16-wave barrier-coupled block/CU). Partial float2 -> ws.
//   K2: 256 blocks x 256 thr: sum 4 partials, broadcast scalar, float4 stores.

__global__ __launch_bounds__(256)
void attn_partial_kernel(const float* __restrict__ x,   // [B,C,N]
                         const float* __restrict__ Wk,  // [C,C]
                         const float* __restrict__ Wv,  // [C,C]
                         float2* __restrict__ part)     // [B*C*4]
{
    const int blk  = blockIdx.x;        // bc*4 + quarter
    const int bc   = blk >> 2;
    const int q    = blk & 3;
    const int b    = bc >> 6;
    const int c    = bc & 63;
    const int tid  = threadIdx.x;       // 0..255
    const int lane = tid & 63;
    const int wave = tid >> 6;          // 0..3
    const int n    = q * NQUARTER + tid;

    __shared__ float wk_s[CH];
    __shared__ float wv_s[CH];
    __shared__ float red_a[4];
    __shared__ float red_b[4];

    if (tid < CH)          wk_s[tid]      = Wk[c * CH + tid];
    else if (tid < 2 * CH) wv_s[tid - CH] = Wv[c * CH + (tid - CH)];
    __syncthreads();

    // ---- projections K[b,c,n], V[b,c,n] ----
    const float* xb = x + (size_t)b * CH * NSEQ + n;
    float kacc = 0.f, vacc = 0.f;
    #pragma unroll
    for (int cp = 0; cp < CH; ++cp) {
        const float xv = xb[cp * NSEQ];          // coalesced 256B/wave
        kacc = fmaf(wk_s[cp], xv, kacc);
        vacc = fmaf(wv_s[cp], xv, vacc);
    }

    const float e = __expf(-kacc * INV_SQRT_D);
    float se  = e;
    float sev = e * vacc;

    #pragma unroll
    for (int off = 32; off > 0; off >>= 1) {
        se  += __shfl_xor(se,  off);
        sev += __shfl_xor(sev, off);
    }
    if (lane == 0) { red_a[wave] = se; red_b[wave] = sev; }
    __syncthreads();

    if (tid == 0) {
        float2 p;
        p.x = red_a[0] + red_a[1] + red_a[2] + red_a[3];
        p.y = red_b[0] + red_b[1] + red_b[2] + red_b[3];
        part[blk] = p;
    }
}

__global__ __launch_bounds__(256)
void attn_broadcast_kernel(const float2* __restrict__ part,  // [B*C*4]
                           float* __restrict__ out)          // [B,C,N]
{
    const int bc  = blockIdx.x;
    const int tid = threadIdx.x;

    const float2 p0 = part[bc * 4 + 0];
    const float2 p1 = part[bc * 4 + 1];
    const float2 p2 = part[bc * 4 + 2];
    const float2 p3 = part[bc * 4 + 3];
    const float tse  = (p0.x + p1.x) + (p2.x + p3.x);
    const float tsev = (p0.y + p1.y) + (p2.y + p3.y);
    const float o = tsev / tse;

    float4 ov; ov.x = o; ov.y = o; ov.z = o; ov.w = o;
    *reinterpret_cast<float4*>(out + (size_t)bc * NSEQ + tid * 4) = ov;
}

extern "C" void kernel_launch(void* const* d_in, const int* in_sizes, int n_in,
                              void* d_out, int out_size, void* d_ws, size_t ws_size,
                              hipStream_t stream) {
    const float* x  = (const float*)d_in[0];
    // d_in[1] = Wq — dead (softmax over keys cancels q); never read.
    const float* Wk = (const float*)d_in[2];
    const float* Wv = (const float*)d_in[3];
    float* out = (float*)d_out;
    float2* part = (float2*)d_ws;   // 1024 * 8B = 8 KiB scratch

    attn_partial_kernel<<<BATCH * CH * 4, 256, 0, stream>>>(x, Wk, Wv, part);
    attn_broadcast_kernel<<<BATCH * CH, 256, 0, stream>>>(part, out);
}